// Round 5
// baseline (900.799 us; speedup 1.0000x reference)
//
#include <hip/hip_runtime.h>
#include <math.h>

#define N_ATOMS 50000
#define N_PAIRS 1600000
#define NF 128
#define NRBF 20
#define PADCAP 2050000              // padded edge-slot capacity (actual ~1.985M)
#define NTILE_CAP (PADCAP / 16)     // 128125
#define NBLK 196                    // ceil(50000/256)

typedef _Float16 half8 __attribute__((ext_vector_type(8)));
typedef float floatx4 __attribute__((ext_vector_type(4)));
typedef unsigned long long u64;
typedef u64 u64x2 __attribute__((ext_vector_type(2)));
typedef unsigned short u16;

__device__ __forceinline__ float sspf(float x) {
    float t = __expf(-fabsf(x));
    return fmaxf(x, 0.0f) + __logf(1.0f + t) - 0.69314718055994530942f;
}

// feature permutation: position i=16g+m holds feature 8m+g (bijection on 0..127)
__device__ __forceinline__ int permf(int i) { return ((i & 15) << 3) | (i >> 4); }

// Swizzled LDS layout for a [128 rows x 128 fp16] matrix (256 B rows).
__device__ __forceinline__ int swz16(int row, int k8) {
    return row * 256 + ((k8 ^ (row & 15)) << 4);
}

// ---------------- prep: W fp16 transposed+swizzled images + zero histogram.
// b==0: W_in std. b==1/2/3: Wf2/Wo1/Wo2 col-permuted (rows natural). ----------------
__global__ __launch_bounds__(256) void prep_kernel(
    const float* __restrict__ W_in, const float* __restrict__ Wf2,
    const float* __restrict__ Wo1, const float* __restrict__ Wo2,
    _Float16* __restrict__ Wimg, int* __restrict__ woffs)
{
    const int b = blockIdx.x;   // 0..3
    const float* W = (b == 0) ? W_in : (b == 1) ? Wf2 : (b == 2) ? Wo1 : Wo2;
    char* img = (char*)(Wimg + b * 16384);
    for (int i = threadIdx.x; i < 128 * 128; i += 256) {
        int c = i & 127, k = i >> 7;
        float v = (b == 0) ? W[k * 128 + c] : W[k * 128 + permf(c)];
        *(_Float16*)(img + swz16(c, k >> 3) + ((k & 7) << 1)) = (_Float16)v;
    }
    for (int i = b * 256 + threadIdx.x; i < N_ATOMS; i += 1024) woffs[i] = 0;
}

// ---------------- parallel scan pipeline ----------------
__global__ __launch_bounds__(256) void scanA_kernel(
    const int* __restrict__ cnt, int* __restrict__ bsum)
{
    __shared__ int red[256];
    const int t = threadIdx.x;
    int i = blockIdx.x * 256 + t;
    int c = (i < N_ATOMS) ? cnt[i] : 0;
    red[t] = (c + 15) >> 4;
    __syncthreads();
    for (int s = 128; s > 0; s >>= 1) {
        if (t < s) red[t] += red[t + s];
        __syncthreads();
    }
    if (t == 0) bsum[blockIdx.x] = red[0];
}

__global__ __launch_bounds__(256) void scanB_kernel(
    const int* __restrict__ bsum, int* __restrict__ bpre, int* __restrict__ meta)
{
    __shared__ int sc[256];
    const int t = threadIdx.x;
    int v = (t < NBLK) ? bsum[t] : 0;
    sc[t] = v;
    __syncthreads();
    for (int off = 1; off < 256; off <<= 1) {
        int x = (t >= off) ? sc[t - off] : 0;
        __syncthreads();
        sc[t] += x;
        __syncthreads();
    }
    if (t < NBLK) bpre[t] = sc[t] - v;
    if (t == 255) meta[0] = sc[255] < NTILE_CAP ? sc[255] : NTILE_CAP;
}

// C: local scan + slot starts + descriptors + zero-fill padded eid slots
__global__ __launch_bounds__(256) void scanC_kernel(
    int* __restrict__ woffs, const int* __restrict__ bpre,
    int* __restrict__ desc, int* __restrict__ eid_s)
{
    __shared__ int sc[256];
    const int t = threadIdx.x;
    int i = blockIdx.x * 256 + t;
    int c = (i < N_ATOMS) ? woffs[i] : 0;
    int nt = (c + 15) >> 4;
    sc[t] = nt;
    __syncthreads();
    for (int off = 1; off < 256; off <<= 1) {
        int x = (t >= off) ? sc[t - off] : 0;
        __syncthreads();
        sc[t] += x;
        __syncthreads();
    }
    int tb = bpre[blockIdx.x] + sc[t] - nt;
    if (i < N_ATOMS) {
        woffs[i] = tb * 16;                      // padded slot start (scatter bumps)
        for (int k = 0; k < nt; ++k) {
            int nv = c - k * 16; if (nv > 16) nv = 16;
            if (tb + k < NTILE_CAP) desc[tb + k] = (i << 5) | nv;
        }
        int padlo = tb * 16 + c, padhi = (tb + nt) * 16;
        if (padhi > PADCAP) padhi = PADCAP;
        for (int s = padlo; s < padhi; ++s) eid_s[s] = 0;   // safe gather target
    }
}

// ---------------- scatter: edge-ids only (4B per slot) ----------------
__global__ __launch_bounds__(256) void scatter_eid_kernel(
    const int* __restrict__ idx_i, int* __restrict__ woffs, int* __restrict__ eid_s)
{
    for (int e = blockIdx.x * 256 + threadIdx.x; e < N_PAIRS; e += gridDim.x * 256) {
        int pos = atomicAdd(&woffs[idx_i[e]], 1);
        if (pos < PADCAP) eid_s[pos] = e;
    }
}

// ---------------- staging: straight 32KB copy of pre-swizzled image ----------------
template<int NTHR>
__device__ __forceinline__ void stage_img(const _Float16* __restrict__ img, char* dst, int t) {
    const float4* s = (const float4*)img;
    float4* d = (float4*)dst;
    for (int i = t; i < 2048; i += NTHR) d[i] = s[i];
}

// ---------------- generic 128x128 gemm + fused agg-zero / hist / record-convert ----
template<typename TIN, typename TOUT, bool SSP_OUT, bool ZERO, bool HIST, bool CVT>
__global__ __launch_bounds__(256) void gemm_mfma_kernel(
    const TIN* __restrict__ A, const _Float16* __restrict__ Wimg,
    const float* __restrict__ bias, TOUT* __restrict__ out, int M,
    float* __restrict__ zbuf, int zcount4,
    const int* __restrict__ hidx, int* __restrict__ hcnt,
    const float* __restrict__ cf, const float* __restrict__ crc,
    const int* __restrict__ cj, u64* __restrict__ cdst)
{
    __shared__ char sW[32768];
    const int t = threadIdx.x;
    const int w = t >> 6, lane = t & 63, m = lane & 15, q = lane >> 4;

    if (ZERO) {
        float4 z = {0.f, 0.f, 0.f, 0.f};
        for (int i = blockIdx.x * 256 + t; i < zcount4; i += gridDim.x * 256)
            ((float4*)zbuf)[i] = z;
    }
    if (HIST) {
        for (int e = blockIdx.x * 256 + t; e < N_PAIRS; e += gridDim.x * 256)
            atomicAdd(&hcnt[hidx[e]], 1);
    }
    if (CVT) {
        for (int e = blockIdx.x * 256 + t; e < N_PAIRS; e += gridDim.x * 256) {
            const float4* fr = (const float4*)(cf + (size_t)e * NRBF);
            u64 qw[6];
            #pragma unroll
            for (int v = 0; v < 5; ++v) {
                float4 fv = fr[v];
                union { u64 u; _Float16 hx[4]; } pk;
                pk.hx[0] = (_Float16)fv.x; pk.hx[1] = (_Float16)fv.y;
                pk.hx[2] = (_Float16)fv.z; pk.hx[3] = (_Float16)fv.w;
                qw[v] = pk.u;
            }
            qw[5] = (u64)__float_as_uint(crc[e]) | ((u64)(u16)cj[e] << 32);
            u64* dst = cdst + (size_t)e * 6;
            u64x2 p0 = {qw[0], qw[1]}, p1 = {qw[2], qw[3]}, p2 = {qw[4], qw[5]};
            *(u64x2*)(dst + 0) = p0;
            *(u64x2*)(dst + 2) = p1;
            *(u64x2*)(dst + 4) = p2;
        }
    }
    stage_img<256>(Wimg, sW, t);
    float bv[8];
    #pragma unroll
    for (int g = 0; g < 8; ++g) bv[g] = bias[g * 16 + m];
    __syncthreads();

    const floatx4 zero4 = {0.f, 0.f, 0.f, 0.f};
    const int ntiles = (M + 63) >> 6;
    for (int tile = blockIdx.x; tile < ntiles; tile += gridDim.x) {
        const int arow = tile * 64 + w * 16 + m;
        half8 a[4];
        if (arow < M) {
            const TIN* ap = A + (size_t)arow * 128;
            #pragma unroll
            for (int s = 0; s < 4; ++s) {
                if (sizeof(TIN) == 2) {
                    a[s] = *(const half8*)(ap + s * 32 + q * 8);
                } else {
                    float4 u0 = *(const float4*)((const float*)ap + s * 32 + q * 8);
                    float4 u1 = *(const float4*)((const float*)ap + s * 32 + q * 8 + 4);
                    a[s][0] = (_Float16)u0.x; a[s][1] = (_Float16)u0.y;
                    a[s][2] = (_Float16)u0.z; a[s][3] = (_Float16)u0.w;
                    a[s][4] = (_Float16)u1.x; a[s][5] = (_Float16)u1.y;
                    a[s][6] = (_Float16)u1.z; a[s][7] = (_Float16)u1.w;
                }
            }
        } else {
            #pragma unroll
            for (int s = 0; s < 4; ++s) a[s] = (half8){};
        }
        floatx4 acc[8];
        #pragma unroll
        for (int g = 0; g < 8; ++g) {
            floatx4 c = zero4;
            #pragma unroll
            for (int s = 0; s < 4; ++s) {
                half8 b = *(const half8*)(sW + swz16(g * 16 + m, 4 * s + q));
                c = __builtin_amdgcn_mfma_f32_16x16x32_f16(a[s], b, c, 0, 0, 0);
            }
            acc[g] = c;
        }
        #pragma unroll
        for (int r = 0; r < 4; ++r) {
            const int grow = tile * 64 + w * 16 + q * 4 + r;
            if (grow < M) {
                TOUT* op = out + (size_t)grow * 128;
                #pragma unroll
                for (int g = 0; g < 8; ++g) {
                    float v = acc[g][r] + bv[g];
                    if (SSP_OUT) v = sspf(v);
                    op[g * 16 + m] = (TOUT)v;
                }
            }
        }
    }
}

// ---------------- fused output: out = ssp(agg@Wo1+bo1)@Wo2+bo2 ----------------
__global__ __launch_bounds__(256) void out_kernel(
    const float* __restrict__ A, const _Float16* __restrict__ Wimg1,
    const _Float16* __restrict__ Wimg2, const float* __restrict__ bo1,
    const float* __restrict__ bo2, float* __restrict__ out, int M)
{
    __shared__ char sW[65536];                  // [0,32K)=Wo1 col-perm, [32K,64K)=Wo2 col-perm
    __shared__ char sS[4][4096];                // wave-private 16-row slabs
    const int t = threadIdx.x;
    const int w = t >> 6, lane = t & 63, m = lane & 15, q = lane >> 4;

    stage_img<256>(Wimg1, sW, t);
    stage_img<256>(Wimg2, sW + 32768, t);
    float4 o1lo = *(const float4*)(bo1 + m * 8), o1hi = *(const float4*)(bo1 + m * 8 + 4);
    float4 o2lo = *(const float4*)(bo2 + m * 8), o2hi = *(const float4*)(bo2 + m * 8 + 4);
    float b1v[8] = {o1lo.x, o1lo.y, o1lo.z, o1lo.w, o1hi.x, o1hi.y, o1hi.z, o1hi.w};
    float b2v[8] = {o2lo.x, o2lo.y, o2lo.z, o2lo.w, o2hi.x, o2hi.y, o2hi.z, o2hi.w};
    __syncthreads();

    char* mySS = sS[w];
    const floatx4 zero4 = {0.f, 0.f, 0.f, 0.f};
    const int ntiles = (M + 63) >> 6;
    for (int tile = blockIdx.x; tile < ntiles; tile += gridDim.x) {
        const int arow = tile * 64 + w * 16 + m;
        half8 a[4];
        if (arow < M) {
            const float* ap = A + (size_t)arow * 128;
            #pragma unroll
            for (int s = 0; s < 4; ++s) {
                float4 u0 = *(const float4*)(ap + s * 32 + q * 8);
                float4 u1 = *(const float4*)(ap + s * 32 + q * 8 + 4);
                a[s][0] = (_Float16)u0.x; a[s][1] = (_Float16)u0.y;
                a[s][2] = (_Float16)u0.z; a[s][3] = (_Float16)u0.w;
                a[s][4] = (_Float16)u1.x; a[s][5] = (_Float16)u1.y;
                a[s][6] = (_Float16)u1.z; a[s][7] = (_Float16)u1.w;
            }
        } else {
            #pragma unroll
            for (int s = 0; s < 4; ++s) a[s] = (half8){};
        }
        // stage 1: ct[g] = A@Wo1 col m*8+g (col-permuted Wo1 image)
        floatx4 ct[8];
        #pragma unroll
        for (int g = 0; g < 8; ++g) {
            floatx4 c = zero4;
            #pragma unroll
            for (int s = 0; s < 4; ++s) {
                half8 b = *(const half8*)(sW + swz16(g * 16 + m, 4 * s + q));
                c = __builtin_amdgcn_mfma_f32_16x16x32_f16(a[s], b, c, 0, 0, 0);
            }
            ct[g] = c;
        }
        // ssp + packed b128 slab write (natural feature order)
        #pragma unroll
        for (int r = 0; r < 4; ++r) {
            half8 hp;
            #pragma unroll
            for (int g = 0; g < 8; ++g) hp[g] = (_Float16)sspf(ct[g][r] + b1v[g]);
            *(half8*)(mySS + swz16(q * 4 + r, m)) = hp;
        }
        half8 a2[4];
        #pragma unroll
        for (int s = 0; s < 4; ++s)
            a2[s] = *(const half8*)(mySS + swz16(m, 4 * s + q));
        // stage 2: out = t@Wo2 + bo2 (k natural, out-cols permuted)
        floatx4 acc[8];
        #pragma unroll
        for (int g = 0; g < 8; ++g) {
            floatx4 c = zero4;
            #pragma unroll
            for (int s = 0; s < 4; ++s) {
                half8 b = *(const half8*)(sW + 32768 + swz16(g * 16 + m, 4 * s + q));
                c = __builtin_amdgcn_mfma_f32_16x16x32_f16(a2[s], b, c, 0, 0, 0);
            }
            acc[g] = c;
        }
        #pragma unroll
        for (int r = 0; r < 4; ++r) {
            const int grow = tile * 64 + w * 16 + q * 4 + r;
            if (grow < M) {
                float* op = out + (size_t)grow * 128 + m * 8;
                float4 lo = {acc[0][r] + b2v[0], acc[1][r] + b2v[1],
                             acc[2][r] + b2v[2], acc[3][r] + b2v[3]};
                float4 hi = {acc[4][r] + b2v[4], acc[5][r] + b2v[5],
                             acc[6][r] + b2v[6], acc[7][r] + b2v[7]};
                *(float4*)op = lo;
                *(float4*)(op + 4) = hi;
            }
        }
    }
}

// ---------------- edge kernel: 8 waves, eid-indirect L3-resident record gathers,
// packed b128 slab writes, register accumulation, one atomic flush per run ----------------
__global__ __launch_bounds__(512) void edge_kernel(
    const u64* __restrict__ f16c, const int* __restrict__ eid_s,
    const int* __restrict__ desc, const int* __restrict__ meta,
    const float* __restrict__ Wf1, const float* __restrict__ bf1,
    const _Float16* __restrict__ Wf2img, const float* __restrict__ bf2,
    const _Float16* __restrict__ h, float* __restrict__ agg)
{
    __shared__ char sW2[32768];
    __shared__ char sS[8][4096];   // wave-private 16-row slabs
    const int t = threadIdx.x;
    const int w = t >> 6, lane = t & 63, m = lane & 15, q = lane >> 4;

    stage_img<512>(Wf2img, sW2, t);
    half8 bW1[8];
    #pragma unroll
    for (int g = 0; g < 8; ++g) {
        #pragma unroll
        for (int j = 0; j < 8; ++j) {
            int k = q * 8 + j;
            bW1[g][j] = (k < NRBF) ? (_Float16)Wf1[k * 128 + m * 8 + g] : (_Float16)0.0f;
        }
    }
    float4 b1lo = *(const float4*)(bf1 + m * 8), b1hi = *(const float4*)(bf1 + m * 8 + 4);
    float4 b2lo = *(const float4*)(bf2 + m * 8), b2hi = *(const float4*)(bf2 + m * 8 + 4);
    float bf1r[8] = {b1lo.x, b1lo.y, b1lo.z, b1lo.w, b1hi.x, b1hi.y, b1hi.z, b1hi.w};
    float bf2r[8] = {b2lo.x, b2lo.y, b2lo.z, b2lo.w, b2hi.x, b2hi.y, b2hi.z, b2hi.w};
    __syncthreads();   // no barriers after this

    char* mySS = sS[w];
    const floatx4 zero4 = {0.f, 0.f, 0.f, 0.f};
    const int NT = meta[0];
    const int nw = gridDim.x * 8;
    const int wid = blockIdx.x * 8 + w;
    const int T = (NT + nw - 1) / nw;
    int t0 = wid * T, t1 = t0 + T;
    if (t1 > NT) t1 = NT;
    if (t0 >= t1) return;

    auto loadtile = [&](int tt, int& d_, u64& x0_, u64& x1_, u64* rcj) {
        d_ = desc[tt];
        int4 e4 = *(const int4*)&eid_s[tt * 16 + q * 4];
        int em = eid_s[tt * 16 + m];
        const u64* base = f16c + (size_t)em * 6;
        u64 x0 = 0, x1 = 0;
        if (q < 2)       { x0 = base[2 * q]; x1 = base[2 * q + 1]; }
        else if (q == 2) { x0 = base[4]; }
        x0_ = x0; x1_ = x1;
        rcj[0] = f16c[(size_t)e4.x * 6 + 5];
        rcj[1] = f16c[(size_t)e4.y * 6 + 5];
        rcj[2] = f16c[(size_t)e4.z * 6 + 5];
        rcj[3] = f16c[(size_t)e4.w * 6 + 5];
    };

    int d; u64 u0, u1; u64 rcj[4];
    loadtile(t0, d, u0, u1, rcj);

    float racc[8];
    #pragma unroll
    for (int g = 0; g < 8; ++g) racc[g] = 0.f;

    for (int tt = t0; tt < t1; ++tt) {
        const int nv = d & 31;
        const int atom = d >> 5;

        float rc[4]; int jm[4];
        #pragma unroll
        for (int r = 0; r < 4; ++r) {
            bool ok = (q * 4 + r) < nv;
            rc[r] = ok ? __uint_as_float((unsigned)rcj[r]) : 0.f;
            jm[r] = ok ? (int)((rcj[r] >> 32) & 0xffffu) : 0;
        }
        half8 hv[4];
        #pragma unroll
        for (int r = 0; r < 4; ++r)
            hv[r] = *(const half8*)(h + (size_t)jm[r] * NF + m * 8);

        int nd = 0; u64 nu0 = 0, nu1 = 0; u64 nrcj[4] = {0, 0, 0, 0};
        if (tt + 1 < t1) loadtile(tt + 1, nd, nu0, nu1, nrcj);

        union { u64 uu[2]; half8 v; } cv;
        cv.uu[0] = u0; cv.uu[1] = u1;
        half8 a1 = cv.v;
        if (m >= nv) a1 = (half8){};

        floatx4 c1[8];
        #pragma unroll
        for (int g = 0; g < 8; ++g)
            c1[g] = __builtin_amdgcn_mfma_f32_16x16x32_f16(a1, bW1[g], zero4, 0, 0, 0);

        // ssp + packed b128 write: row q*4+r, features m*8..m*8+7 (natural order)
        #pragma unroll
        for (int r = 0; r < 4; ++r) {
            half8 hp;
            #pragma unroll
            for (int g = 0; g < 8; ++g) hp[g] = (_Float16)sspf(c1[g][r] + bf1r[g]);
            *(half8*)(mySS + swz16(q * 4 + r, m)) = hp;
        }
        half8 a2[4];
        #pragma unroll
        for (int s = 0; s < 4; ++s)
            a2[s] = *(const half8*)(mySS + swz16(m, 4 * s + q));

        #pragma unroll
        for (int g = 0; g < 8; ++g) {
            floatx4 c = zero4;
            #pragma unroll
            for (int s = 0; s < 4; ++s) {
                half8 b = *(const half8*)(sW2 + swz16(g * 16 + m, 4 * s + q));
                c = __builtin_amdgcn_mfma_f32_16x16x32_f16(a2[s], b, c, 0, 0, 0);
            }
            #pragma unroll
            for (int r = 0; r < 4; ++r)
                racc[g] += ((c[r] + bf2r[g]) * rc[r]) * (float)hv[r][g];
        }

        bool last = (tt + 1 >= t1);
        if (last || (nd >> 5) != atom) {
            float* arow = agg + (size_t)atom * NF + m * 8;
            #pragma unroll
            for (int g = 0; g < 8; ++g) {
                float v = racc[g];
                v += __shfl_xor(v, 16, 64);
                v += __shfl_xor(v, 32, 64);
                if (q == 0) atomicAdd(&arow[g], v);
                racc[g] = 0.f;
            }
        }
        d = nd; u0 = nu0; u1 = nu1;
        rcj[0] = nrcj[0]; rcj[1] = nrcj[1]; rcj[2] = nrcj[2]; rcj[3] = nrcj[3];
    }
}

// ---------------- fallback edge kernel (atomic-per-edge, consistent layouts) ----------------
__global__ __launch_bounds__(256) void edge_atomic_kernel(
    const float* __restrict__ f_ij, const float* __restrict__ rcut,
    const float* __restrict__ Wf1, const float* __restrict__ bf1,
    const _Float16* __restrict__ Wf2img, const float* __restrict__ bf2,
    const int* __restrict__ idx_i, const int* __restrict__ idx_j,
    const _Float16* __restrict__ h, float* __restrict__ agg)
{
    __shared__ char sW2[32768];
    __shared__ char sS[4][4096];
    const int NTILES = N_PAIRS / 64;
    const int t = threadIdx.x;
    const int w = t >> 6, lane = t & 63, m = lane & 15, q = lane >> 4;

    stage_img<256>(Wf2img, sW2, t);
    half8 bW1[8];
    #pragma unroll
    for (int g = 0; g < 8; ++g) {
        #pragma unroll
        for (int j = 0; j < 8; ++j) {
            int k = q * 8 + j;
            bW1[g][j] = (k < NRBF) ? (_Float16)Wf1[k * 128 + m * 8 + g] : (_Float16)0.0f;
        }
    }
    float4 b1lo = *(const float4*)(bf1 + m * 8), b1hi = *(const float4*)(bf1 + m * 8 + 4);
    float4 b2lo = *(const float4*)(bf2 + m * 8), b2hi = *(const float4*)(bf2 + m * 8 + 4);
    float bf1r[8] = {b1lo.x, b1lo.y, b1lo.z, b1lo.w, b1hi.x, b1hi.y, b1hi.z, b1hi.w};
    float bf2r[8] = {b2lo.x, b2lo.y, b2lo.z, b2lo.w, b2hi.x, b2hi.y, b2hi.z, b2hi.w};
    __syncthreads();

    char* mySS = sS[w];
    const floatx4 zero4 = {0.f, 0.f, 0.f, 0.f};
    const float4 fz = {0.f, 0.f, 0.f, 0.f};

    for (int tile = blockIdx.x; tile < NTILES; tile += gridDim.x) {
        const int e0 = tile * 64 + w * 16;
        float4 f0 = fz, f1 = fz;
        const float* fb = f_ij + (size_t)(e0 + m) * NRBF + q * 8;
        if (q < 2)      { f0 = *(const float4*)fb; f1 = *(const float4*)(fb + 4); }
        else if (q == 2){ f0 = *(const float4*)fb; }
        int4 jj4 = *(const int4*)&idx_j[e0 + q * 4];
        int4 ii4 = *(const int4*)&idx_i[e0 + q * 4];
        float4 rc4 = *(const float4*)&rcut[e0 + q * 4];
        int jj[4] = {jj4.x, jj4.y, jj4.z, jj4.w};
        half8 hv[4];
        #pragma unroll
        for (int r = 0; r < 4; ++r)
            hv[r] = *(const half8*)(h + (size_t)jj[r] * NF + m * 8);

        half8 a1;
        a1[0]=(_Float16)f0.x; a1[1]=(_Float16)f0.y; a1[2]=(_Float16)f0.z; a1[3]=(_Float16)f0.w;
        a1[4]=(_Float16)f1.x; a1[5]=(_Float16)f1.y; a1[6]=(_Float16)f1.z; a1[7]=(_Float16)f1.w;
        floatx4 c1[8];
        #pragma unroll
        for (int g = 0; g < 8; ++g)
            c1[g] = __builtin_amdgcn_mfma_f32_16x16x32_f16(a1, bW1[g], zero4, 0, 0, 0);

        #pragma unroll
        for (int r = 0; r < 4; ++r) {
            half8 hp;
            #pragma unroll
            for (int g = 0; g < 8; ++g) hp[g] = (_Float16)sspf(c1[g][r] + bf1r[g]);
            *(half8*)(mySS + swz16(q * 4 + r, m)) = hp;
        }
        half8 a2[4];
        #pragma unroll
        for (int s = 0; s < 4; ++s)
            a2[s] = *(const half8*)(mySS + swz16(m, 4 * s + q));

        floatx4 acc[8];
        #pragma unroll
        for (int g = 0; g < 8; ++g) {
            floatx4 c = zero4;
            #pragma unroll
            for (int s = 0; s < 4; ++s) {
                half8 b = *(const half8*)(sW2 + swz16(g * 16 + m, 4 * s + q));
                c = __builtin_amdgcn_mfma_f32_16x16x32_f16(a2[s], b, c, 0, 0, 0);
            }
            acc[g] = c;
        }
        int ii[4] = {ii4.x, ii4.y, ii4.z, ii4.w};
        float rc[4] = {rc4.x, rc4.y, rc4.z, rc4.w};
        #pragma unroll
        for (int r = 0; r < 4; ++r) {
            float* arow = agg + (size_t)ii[r] * 128 + m * 8;
            #pragma unroll
            for (int g = 0; g < 8; ++g) {
                float wij = (acc[g][r] + bf2r[g]) * rc[r];
                atomicAdd(&arow[g], (float)hv[r][g] * wij);
            }
        }
    }
}

extern "C" void kernel_launch(void* const* d_in, const int* in_sizes, int n_in,
                              void* d_out, int out_size, void* d_ws, size_t ws_size,
                              hipStream_t stream) {
    const float* x     = (const float*)d_in[0];
    const float* f_ij  = (const float*)d_in[1];
    const float* rcutp = (const float*)d_in[2];
    const float* W_in  = (const float*)d_in[3];
    const float* b_in  = (const float*)d_in[4];
    const float* Wf1   = (const float*)d_in[5];
    const float* bf1   = (const float*)d_in[6];
    const float* Wf2   = (const float*)d_in[7];
    const float* bf2   = (const float*)d_in[8];
    const float* Wo1   = (const float*)d_in[9];
    const float* bo1   = (const float*)d_in[10];
    const float* Wo2   = (const float*)d_in[11];
    const float* bo2   = (const float*)d_in[12];
    const int* idx_i   = (const int*)d_in[13];
    const int* idx_j   = (const int*)d_in[14];
    float* out = (float*)d_out;

    // workspace layout (16B-aligned offsets)
    char* ws = (char*)d_ws;
    float*     agg   = (float*)ws;                       // 25,600,000
    _Float16*  h     = (_Float16*)(ws + 25600000);       // 12,800,000
    _Float16*  Wimg  = (_Float16*)(ws + 38400000);       //    131,072
    int*       woffs = (int*)(ws + 38531072);            //    200,000
    int*       meta  = (int*)(ws + 38731072);            //         16
    int*       bsum  = (int*)(ws + 38731088);            //        800
    int*       bpre  = (int*)(ws + 38731888);            //        800
    int*       desc  = (int*)(ws + 38732688);            //    512,512
    int*       eid_s = (int*)(ws + 39245200);            //  8,200,000
    u64*       f16c  = (u64*)(ws + 47445200);            // 76,800,000 (1.6M x 48B)
    const size_t NEED = 124245200;

    const int zc4 = N_ATOMS * NF / 4;
    prep_kernel<<<dim3(4), 256, 0, stream>>>(W_in, Wf2, Wo1, Wo2, Wimg, woffs);

    if (ws_size >= NEED) {
        // gemm1 with fused agg-zero, histogram, and f-record convert
        gemm_mfma_kernel<float, _Float16, false, true, true, true>
            <<<dim3(782), 256, 0, stream>>>(x, Wimg, b_in, h, N_ATOMS, agg, zc4,
                                            idx_i, woffs, f_ij, rcutp, idx_j, f16c);
        scanA_kernel<<<dim3(NBLK), 256, 0, stream>>>(woffs, bsum);
        scanB_kernel<<<dim3(1), 256, 0, stream>>>(bsum, bpre, meta);
        scanC_kernel<<<dim3(NBLK), 256, 0, stream>>>(woffs, bpre, desc, eid_s);
        scatter_eid_kernel<<<dim3(1024), 256, 0, stream>>>(idx_i, woffs, eid_s);
        edge_kernel<<<dim3(512), 512, 0, stream>>>(
            f16c, eid_s, desc, meta, Wf1, bf1, Wimg + 16384, bf2, h, agg);
    } else {
        gemm_mfma_kernel<float, _Float16, false, true, false, false>
            <<<dim3(782), 256, 0, stream>>>(x, Wimg, b_in, h, N_ATOMS, agg, zc4,
                                            nullptr, nullptr, nullptr, nullptr,
                                            nullptr, nullptr);
        edge_atomic_kernel<<<dim3(768), 256, 0, stream>>>(
            f_ij, rcutp, Wf1, bf1, Wimg + 16384, bf2, idx_i, idx_j, h, agg);
    }

    // fused: out = ssp(agg@Wo1+bo1)@Wo2+bo2
    out_kernel<<<dim3(782), 256, 0, stream>>>(
        agg, Wimg + 32768, Wimg + 49152, bo1, bo2, out, N_ATOMS);
}